// Round 9
// baseline (8394.147 us; speedup 1.0000x reference)
//
#include <hip/hip_runtime.h>

#define B_   32
#define H_   16
#define L_   577
#define D_   1024
#define CK   64
#define LP   576    // L-1 patches
#define DOM  54
#define NSEL 55     // DOM + CLS
#define NR   522    // LP - DOM
#define CTX  10
#define NMERGE 512  // NR - CTX
#define BL   (B_ * LP)

// ---- DIAGNOSTIC ROUND: each kernel's body repeated R times so it rises ----
// ---- above the ~410us harness fills into rocprof top-5. Results are     ----
// ---- bit-identical to the unamplified R8 kernel (idempotent rewrites).  ----
#define RPRE 256
#define RSEL 160
#define RASG 512
#define ROUT 48
#define CLOBBER() asm volatile("" ::: "memory")

// remain-list position for merge index m: p = m + min(m/51,9) + 1
__device__ __forceinline__ int remain_pos(int m) {
    int k = m / 51; if (k > 9) k = 9;
    return m + k + 1;
}

// block-wide sum over 576 threads (9 waves) — proven R1-R3
__device__ float block_sum576(float v) {
    __shared__ float red9[9];
    __shared__ float tot;
    for (int o = 32; o; o >>= 1) v += __shfl_xor(v, o);
    if ((threadIdx.x & 63) == 0) red9[threadIdx.x >> 6] = v;
    __syncthreads();
    if (threadIdx.x < 16) {
        float s = (threadIdx.x < 9) ? red9[threadIdx.x] : 0.f;
        for (int o = 8; o; o >>= 1) s += __shfl_xor(s, o);
        if (threadIdx.x == 0) tot = s;
    }
    __syncthreads();
    float r = tot;
    __syncthreads();
    return r;
}

// K0: Sd head-group partials + per-wave cos scores (amplified x RPRE)
__global__ __launch_bounds__(256) void k_pre(
    const float* __restrict__ attn, const float* __restrict__ metric,
    const float* __restrict__ text, float* __restrict__ Sd_part,
    float* __restrict__ cos_arr)
{
    const int bid = blockIdx.x, tid = threadIdx.x;
    for (int rep = 0; rep < RPRE; ++rep) {
        CLOBBER();
        if (bid < 288) {
            int i = bid * 256 + tid;                  // [0, 4*BL)
            int q4 = i / BL, r = i - q4 * BL;
            int b = r / LP, j = r - b * LP;
            size_t base = ((size_t)b * H_ + 4 * q4) * L_ * L_ + 1 + j;
            const size_t LL = (size_t)L_ * L_;
            float s = (attn[base] + attn[base + LL]) +
                      (attn[base + 2 * LL] + attn[base + 3 * LL]);
            Sd_part[i] = s;
        } else {
            int wid = (bid - 288) * 4 + (tid >> 6);   // [0, BL)
            int lane = tid & 63;
            int b = wid / LP, j = wid - b * LP;
            float m = metric[((size_t)(b * L_ + 1 + j)) * CK + lane];
            float t = text[b * CK + lane];
            float d = m * t, ss = m * m, ts = t * t;
            for (int o = 32; o; o >>= 1) {
                d += __shfl_xor(d, o); ss += __shfl_xor(ss, o); ts += __shfl_xor(ts, o);
            }
            if (lane == 0)
                cos_arr[wid] = d / (sqrtf(ss) + 1e-12f) / (sqrtf(ts) + 1e-12f);
        }
    }
}

// K1: z-score + rank-loop top-54 + index lists (amplified x RSEL)
__global__ __launch_bounds__(576) void k_select(
    const float* __restrict__ Sd_part, const float* __restrict__ cos_arr,
    int* __restrict__ dom_idx, int* __restrict__ rem_tok)
{
    const int b = blockIdx.x;
    const int j = threadIdx.x;       // patch 0..575, token j+1
    const int w = j >> 6, lane = j & 63;

    __shared__ float sc[LP];
    __shared__ unsigned long long smask[9];

    for (int rep = 0; rep < RSEL; ++rep) {
        CLOBBER();
        const int idx = b * LP + j;
        float Sd = (Sd_part[idx] + Sd_part[BL + idx]) +
                   (Sd_part[2 * BL + idx] + Sd_part[3 * BL + idx]);
        float cosv = cos_arr[idx];

        float mS = block_sum576(Sd)   * (1.f / LP);
        float dS = Sd - mS;
        float vS = block_sum576(dS * dS) * (1.f / (LP - 1));
        float mC = block_sum576(cosv) * (1.f / LP);
        float dC = cosv - mC;
        float vC = block_sum576(dC * dC) * (1.f / (LP - 1));
        float score = 0.5f * dS / (sqrtf(vS) + 1e-6f) + 0.5f * dC / (sqrtf(vC) + 1e-6f);
        sc[j] = score;
        __syncthreads();

        int rank = 0;
        for (int k = 0; k < LP; ++k) {
            float s = sc[k];
            rank += (s > score) || (s == score && k < j);
        }
        bool selj = (rank < DOM);

        unsigned long long m = __ballot(selj);
        if (lane == 0) smask[w] = m;
        __syncthreads();
        int pre = 0;
        for (int ww = 0; ww < w; ++ww) pre += __popcll(smask[ww]);
        pre += __popcll(smask[w] & ((1ull << lane) - 1ull));

        if (j == 0) dom_idx[b * NSEL] = 0;
        if (selj) dom_idx[b * NSEL + 1 + pre] = j + 1;
        else      rem_tok[b * NR + (j - pre)] = j + 1;
        __syncthreads();   // before sc/smask rewrite next rep
    }
}

// K2: argmax assignment -> packed (tok<<4)|bucket (amplified x RASG)
__global__ __launch_bounds__(128) void k_assign(
    const float* __restrict__ metric, const int* __restrict__ rem_tok,
    int* __restrict__ assign_tok)
{
    const int b = blockIdx.x >> 2, qtr = blockIdx.x & 3;
    const int tid = threadIdx.x;
    __shared__ float tg[CTX * CK];
    __shared__ float tinv[CTX];

    for (int rep = 0; rep < RASG; ++rep) {
        CLOBBER();
        for (int i = tid; i < CTX * CK; i += 128) {
            int kk = i >> 6, c = i & 63;
            int t10 = rem_tok[b * NR + 52 * kk];
            tg[i] = metric[((size_t)(b * L_ + t10)) * CK + c];
        }
        __syncthreads();
        if (tid < CTX) {
            float s2 = 0.f;
            for (int c = 0; c < CK; ++c) { float t = tg[tid * CK + c]; s2 += t * t; }
            tinv[tid] = 1.f / (sqrtf(s2) + 1e-12f);
        }
        __syncthreads();

        const int m = qtr * 128 + tid;
        const int tok = rem_tok[b * NR + remain_pos(m)];
        const float4* row = (const float4*)&metric[((size_t)(b * L_ + tok)) * CK];
        float4 r[16];
        #pragma unroll
        for (int c4 = 0; c4 < 16; ++c4) r[c4] = row[c4];

        float best = -1e30f; int bk = 0;
        #pragma unroll
        for (int k = 0; k < CTX; ++k) {
            float d = 0.f;
            #pragma unroll
            for (int c4 = 0; c4 < 16; ++c4) {
                float4 v = r[c4];
                d += v.x * tg[k*CK + c4*4+0] + v.y * tg[k*CK + c4*4+1] +
                     v.z * tg[k*CK + c4*4+2] + v.w * tg[k*CK + c4*4+3];
            }
            d *= tinv[k];
            if (d > best) { best = d; bk = k; }   // strict >: first max (jnp.argmax)
        }
        assign_tok[b * NMERGE + m] = (tok << 4) | bk;
        __syncthreads();   // before tg rewrite next rep
    }
}

// K3: bucket aggregate + dominant copies (amplified x ROUT)
__global__ __launch_bounds__(256) void k_out(
    const float* __restrict__ hidden, const int* __restrict__ dom_idx,
    const int* __restrict__ rem_tok, const int* __restrict__ assign_tok,
    float* __restrict__ out)
{
    const int blk = blockIdx.x;
    const int tid = threadIdx.x;

    for (int rep = 0; rep < ROUT; ++rep) {
        CLOBBER();
        if (blk < B_ * CTX) {
            const int b = blk / CTX, k = blk % CTX;
            const int w = tid >> 6, lane = tid & 63;
            __shared__ int at[NMERGE];
            __shared__ int toks[NMERGE];
            __shared__ unsigned long long cmask[2][4];

            at[tid]       = assign_tok[b * NMERGE + tid];
            at[tid + 256] = assign_tok[b * NMERGE + tid + 256];
            __syncthreads();
            int a0 = at[tid], a1 = at[tid + 256];
            bool m0 = (a0 & 15) == k, m1 = (a1 & 15) == k;
            unsigned long long bl0 = __ballot(m0), bl1 = __ballot(m1);
            if (lane == 0) { cmask[0][w] = bl0; cmask[1][w] = bl1; }
            __syncthreads();
            int sum0 = 0, pre0 = 0, pre1 = 0;
            #pragma unroll
            for (int ww = 0; ww < 4; ++ww) {
                int p0 = __popcll(cmask[0][ww]);
                sum0 += p0;
                if (ww < w) { pre0 += p0; pre1 += __popcll(cmask[1][ww]); }
            }
            int sum1 = 0;
            #pragma unroll
            for (int ww = 0; ww < 4; ++ww) sum1 += __popcll(cmask[1][ww]);
            unsigned long long lt = (1ull << lane) - 1ull;
            if (m0) toks[pre0 + __popcll(bl0 & lt)] = a0 >> 4;
            if (m1) toks[sum0 + pre1 + __popcll(bl1 & lt)] = a1 >> 4;
            const int cnt = sum0 + sum1;
            __syncthreads();

            const float4* hb = (const float4*)&hidden[((size_t)b * L_) * D_];
            float4 a_0 = make_float4(0,0,0,0), a_1 = a_0, a_2 = a_0, a_3 = a_0;
            float4 a_4 = a_0, a_5 = a_0, a_6 = a_0, a_7 = a_0;
            int i = 0;
            for (; i + 8 <= cnt; i += 8) {
                float4 v0 = hb[(size_t)toks[i+0] * 256 + tid];
                float4 v1 = hb[(size_t)toks[i+1] * 256 + tid];
                float4 v2 = hb[(size_t)toks[i+2] * 256 + tid];
                float4 v3 = hb[(size_t)toks[i+3] * 256 + tid];
                float4 v4 = hb[(size_t)toks[i+4] * 256 + tid];
                float4 v5 = hb[(size_t)toks[i+5] * 256 + tid];
                float4 v6 = hb[(size_t)toks[i+6] * 256 + tid];
                float4 v7 = hb[(size_t)toks[i+7] * 256 + tid];
                a_0.x += v0.x; a_0.y += v0.y; a_0.z += v0.z; a_0.w += v0.w;
                a_1.x += v1.x; a_1.y += v1.y; a_1.z += v1.z; a_1.w += v1.w;
                a_2.x += v2.x; a_2.y += v2.y; a_2.z += v2.z; a_2.w += v2.w;
                a_3.x += v3.x; a_3.y += v3.y; a_3.z += v3.z; a_3.w += v3.w;
                a_4.x += v4.x; a_4.y += v4.y; a_4.z += v4.z; a_4.w += v4.w;
                a_5.x += v5.x; a_5.y += v5.y; a_5.z += v5.z; a_5.w += v5.w;
                a_6.x += v6.x; a_6.y += v6.y; a_6.z += v6.z; a_6.w += v6.w;
                a_7.x += v7.x; a_7.y += v7.y; a_7.z += v7.z; a_7.w += v7.w;
            }
            for (; i < cnt; ++i) {
                float4 v = hb[(size_t)toks[i] * 256 + tid];
                a_0.x += v.x; a_0.y += v.y; a_0.z += v.z; a_0.w += v.w;
            }
            float4 acc;
            acc.x = ((a_0.x + a_1.x) + (a_2.x + a_3.x)) + ((a_4.x + a_5.x) + (a_6.x + a_7.x));
            acc.y = ((a_0.y + a_1.y) + (a_2.y + a_3.y)) + ((a_4.y + a_5.y) + (a_6.y + a_7.y));
            acc.z = ((a_0.z + a_1.z) + (a_2.z + a_3.z)) + ((a_4.z + a_5.z) + (a_6.z + a_7.z));
            acc.w = ((a_0.w + a_1.w) + (a_2.w + a_3.w)) + ((a_4.w + a_5.w) + (a_6.w + a_7.w));

            const int tgt_tok = rem_tok[b * NR + 52 * k];
            float4 bv = hb[(size_t)tgt_tok * 256 + tid];
            float inv = 1.0f / fmaxf((float)cnt, 1.0f);
            float4 o;
            o.x = bv.x + acc.x * inv; o.y = bv.y + acc.y * inv;
            o.z = bv.z + acc.z * inv; o.w = bv.w + acc.w * inv;
            ((float4*)&out[((size_t)(b * 65 + NSEL + k)) * D_])[tid] = o;
            __syncthreads();   // before at/toks rewrite next rep
        } else {
            const int i2 = blk - B_ * CTX;
            const int b = i2 / NSEL, r = i2 % NSEL;
            int tok = dom_idx[b * NSEL + r];
            const float4* src = (const float4*)&hidden[((size_t)(b * L_ + tok)) * D_];
            ((float4*)&out[((size_t)(b * 65 + r)) * D_])[tid] = src[tid];
        }
    }
}

extern "C" void kernel_launch(void* const* d_in, const int* in_sizes, int n_in,
                              void* d_out, int out_size, void* d_ws, size_t ws_size,
                              hipStream_t stream) {
    const float* attn   = (const float*)d_in[0];
    const float* hidden = (const float*)d_in[1];
    const float* metric = (const float*)d_in[2];
    const float* text   = (const float*)d_in[3];
    float* out = (float*)d_out;

    char* ws = (char*)d_ws;
    size_t off = 0;
    auto alloc = [&](size_t bytes) { void* p = ws + off; off = (off + bytes + 255) & ~(size_t)255; return p; };
    float* Sd_part    = (float*)alloc((size_t)4 * BL * 4);
    float* cos_arr    = (float*)alloc((size_t)BL * 4);
    int*   dom_idx    = (int*)  alloc((size_t)B_ * NSEL * 4);
    int*   rem_tok    = (int*)  alloc((size_t)B_ * NR * 4);
    int*   assign_tok = (int*)  alloc((size_t)B_ * NMERGE * 4);

    k_pre   <<<288 + BL / 4, 256, 0, stream>>>(attn, metric, text, Sd_part, cos_arr);
    k_select<<<B_, LP, 0, stream>>>(Sd_part, cos_arr, dom_idx, rem_tok);
    k_assign<<<B_ * 4, 128, 0, stream>>>(metric, rem_tok, assign_tok);
    k_out   <<<B_ * 65, 256, 0, stream>>>(hidden, dom_idx, rem_tok, assign_tok, out);
}

// Round 10
// 67.393 us; speedup vs baseline: 124.5551x; 124.5551x over previous
//
#include <hip/hip_runtime.h>

#define B_   32
#define H_   16
#define L_   577
#define D_   1024
#define CK   64
#define LP   576    // L-1 patches
#define DOM  54
#define NSEL 55     // DOM + CLS
#define NR   522    // LP - DOM
#define CTX  10
#define NMERGE 512  // NR - CTX
#define BL   (B_ * LP)

// remain-list position for merge index m: p = m + min(m/51,9) + 1
__device__ __forceinline__ int remain_pos(int m) {
    int k = m / 51; if (k > 9) k = 9;
    return m + k + 1;
}

__device__ __forceinline__ float wave_sum(float v) {
    for (int o = 32; o; o >>= 1) v += __shfl_xor(v, o);
    return v;
}

// block-wide sum over 576 threads (9 waves) — proven R1-R3
__device__ float block_sum576(float v) {
    __shared__ float red9[9];
    __shared__ float tot;
    for (int o = 32; o; o >>= 1) v += __shfl_xor(v, o);
    if ((threadIdx.x & 63) == 0) red9[threadIdx.x >> 6] = v;
    __syncthreads();
    if (threadIdx.x < 16) {
        float s = (threadIdx.x < 9) ? red9[threadIdx.x] : 0.f;
        for (int o = 8; o; o >>= 1) s += __shfl_xor(s, o);
        if (threadIdx.x == 0) tot = s;
    }
    __syncthreads();
    float r = tot;
    __syncthreads();
    return r;
}

// K0: Sd head-group partials + per-wave cos scores — proven R8
__global__ __launch_bounds__(256) void k_pre(
    const float* __restrict__ attn, const float* __restrict__ metric,
    const float* __restrict__ text, float* __restrict__ Sd_part,
    float* __restrict__ cos_arr)
{
    const int bid = blockIdx.x, tid = threadIdx.x;
    if (bid < 288) {
        int i = bid * 256 + tid;                  // [0, 4*BL)
        int q4 = i / BL, r = i - q4 * BL;
        int b = r / LP, j = r - b * LP;
        size_t base = ((size_t)b * H_ + 4 * q4) * L_ * L_ + 1 + j;
        const size_t LL = (size_t)L_ * L_;
        float s = (attn[base] + attn[base + LL]) +
                  (attn[base + 2 * LL] + attn[base + 3 * LL]);
        Sd_part[i] = s;
    } else {
        int wid = (bid - 288) * 4 + (tid >> 6);   // [0, BL)
        int lane = tid & 63;
        int b = wid / LP, j = wid - b * LP;
        float m = metric[((size_t)(b * L_ + 1 + j)) * CK + lane];
        float t = text[b * CK + lane];
        float d = m * t, ss = m * m, ts = t * t;
        for (int o = 32; o; o >>= 1) {
            d += __shfl_xor(d, o); ss += __shfl_xor(ss, o); ts += __shfl_xor(ts, o);
        }
        if (lane == 0)
            cos_arr[wid] = d / (sqrtf(ss) + 1e-12f) / (sqrtf(ts) + 1e-12f);
    }
}

// K1: z-score + rank-loop top-54 + index lists — proven R8
__global__ __launch_bounds__(576) void k_select(
    const float* __restrict__ Sd_part, const float* __restrict__ cos_arr,
    int* __restrict__ dom_idx, int* __restrict__ rem_tok)
{
    const int b = blockIdx.x;
    const int j = threadIdx.x;       // patch 0..575, token j+1
    const int w = j >> 6, lane = j & 63;

    __shared__ float sc[LP];
    __shared__ unsigned long long smask[9];

    const int idx = b * LP + j;
    float Sd = (Sd_part[idx] + Sd_part[BL + idx]) +
               (Sd_part[2 * BL + idx] + Sd_part[3 * BL + idx]);
    float cosv = cos_arr[idx];

    float mS = block_sum576(Sd)   * (1.f / LP);
    float dS = Sd - mS;
    float vS = block_sum576(dS * dS) * (1.f / (LP - 1));
    float mC = block_sum576(cosv) * (1.f / LP);
    float dC = cosv - mC;
    float vC = block_sum576(dC * dC) * (1.f / (LP - 1));
    float score = 0.5f * dS / (sqrtf(vS) + 1e-6f) + 0.5f * dC / (sqrtf(vC) + 1e-6f);
    sc[j] = score;
    __syncthreads();

    int rank = 0;
    for (int k = 0; k < LP; ++k) {
        float s = sc[k];
        rank += (s > score) || (s == score && k < j);
    }
    bool selj = (rank < DOM);

    unsigned long long m = __ballot(selj);
    if (lane == 0) smask[w] = m;
    __syncthreads();
    int pre = 0;
    for (int ww = 0; ww < w; ++ww) pre += __popcll(smask[ww]);
    pre += __popcll(smask[w] & ((1ull << lane) - 1ull));

    if (j == 0) dom_idx[b * NSEL] = 0;
    if (selj) dom_idx[b * NSEL + 1 + pre] = j + 1;
    else      rem_tok[b * NR + (j - pre)] = j + 1;
}

// K2 (NEW, wave-per-token): argmax assignment -> packed (tok<<4)|bucket
// 4096 blocks x 256 thr: full chip, shuffle-reduce dots, no latency chain.
__global__ __launch_bounds__(256) void k_assign(
    const float* __restrict__ metric, const int* __restrict__ rem_tok,
    int* __restrict__ assign_tok)
{
    const int bid = blockIdx.x;
    const int b = bid >> 7, q = bid & 127;    // 128 blocks per batch
    const int tid = threadIdx.x, wv = tid >> 6, lane = tid & 63;
    __shared__ float tg[CTX * CK];
    __shared__ float tinv[CTX];

    for (int i = tid; i < CTX * CK; i += 256) {
        int kk = i >> 6, c = i & 63;
        tg[i] = metric[((size_t)(b * L_ + rem_tok[b * NR + 52 * kk])) * CK + c];
    }
    __syncthreads();
    for (int k = wv; k < CTX; k += 4) {       // per-wave lane-parallel norms
        float t = tg[k * CK + lane];
        float s2 = wave_sum(t * t);
        if (lane == 0) tinv[k] = 1.f / (sqrtf(s2) + 1e-12f);
    }
    __syncthreads();

    const int m = q * 4 + wv;                 // one token per wave
    const int tok = rem_tok[b * NR + remain_pos(m)];
    float mv = metric[((size_t)(b * L_ + tok)) * CK + lane];   // coalesced 256B

    // merge-row norm dropped: positive scalar, argmax-invariant
    float best = -1e30f; int bk = 0;
    #pragma unroll
    for (int k = 0; k < CTX; ++k) {
        float d = wave_sum(mv * tg[k * CK + lane]) * tinv[k];  // lane-uniform
        if (d > best) { best = d; bk = k; }   // strict >: first max (jnp.argmax)
    }
    if (lane == 0) assign_tok[b * NMERGE + m] = (tok << 4) | bk;
}

// K3: heavy (contextual) blocks first; in-block bucket build + gather — proven R8
__global__ __launch_bounds__(256) void k_out(
    const float* __restrict__ hidden, const int* __restrict__ dom_idx,
    const int* __restrict__ rem_tok, const int* __restrict__ assign_tok,
    float* __restrict__ out)
{
    const int blk = blockIdx.x;
    const int tid = threadIdx.x;

    if (blk < B_ * CTX) {
        const int b = blk / CTX, k = blk % CTX;
        const int w = tid >> 6, lane = tid & 63;
        __shared__ int at[NMERGE];
        __shared__ int toks[NMERGE];
        __shared__ unsigned long long cmask[2][4];

        at[tid]       = assign_tok[b * NMERGE + tid];
        at[tid + 256] = assign_tok[b * NMERGE + tid + 256];
        __syncthreads();
        int a0 = at[tid], a1 = at[tid + 256];
        bool m0 = (a0 & 15) == k, m1 = (a1 & 15) == k;
        unsigned long long bl0 = __ballot(m0), bl1 = __ballot(m1);
        if (lane == 0) { cmask[0][w] = bl0; cmask[1][w] = bl1; }
        __syncthreads();
        int sum0 = 0, pre0 = 0, pre1 = 0;
        #pragma unroll
        for (int ww = 0; ww < 4; ++ww) {
            int p0 = __popcll(cmask[0][ww]);
            sum0 += p0;
            if (ww < w) { pre0 += p0; pre1 += __popcll(cmask[1][ww]); }
        }
        int sum1 = 0;
        #pragma unroll
        for (int ww = 0; ww < 4; ++ww) sum1 += __popcll(cmask[1][ww]);
        unsigned long long lt = (1ull << lane) - 1ull;
        if (m0) toks[pre0 + __popcll(bl0 & lt)] = a0 >> 4;
        if (m1) toks[sum0 + pre1 + __popcll(bl1 & lt)] = a1 >> 4;
        const int cnt = sum0 + sum1;
        __syncthreads();

        const float4* hb = (const float4*)&hidden[((size_t)b * L_) * D_];
        float4 a_0 = make_float4(0,0,0,0), a_1 = a_0, a_2 = a_0, a_3 = a_0;
        float4 a_4 = a_0, a_5 = a_0, a_6 = a_0, a_7 = a_0;
        int i = 0;
        for (; i + 8 <= cnt; i += 8) {
            float4 v0 = hb[(size_t)toks[i+0] * 256 + tid];
            float4 v1 = hb[(size_t)toks[i+1] * 256 + tid];
            float4 v2 = hb[(size_t)toks[i+2] * 256 + tid];
            float4 v3 = hb[(size_t)toks[i+3] * 256 + tid];
            float4 v4 = hb[(size_t)toks[i+4] * 256 + tid];
            float4 v5 = hb[(size_t)toks[i+5] * 256 + tid];
            float4 v6 = hb[(size_t)toks[i+6] * 256 + tid];
            float4 v7 = hb[(size_t)toks[i+7] * 256 + tid];
            a_0.x += v0.x; a_0.y += v0.y; a_0.z += v0.z; a_0.w += v0.w;
            a_1.x += v1.x; a_1.y += v1.y; a_1.z += v1.z; a_1.w += v1.w;
            a_2.x += v2.x; a_2.y += v2.y; a_2.z += v2.z; a_2.w += v2.w;
            a_3.x += v3.x; a_3.y += v3.y; a_3.z += v3.z; a_3.w += v3.w;
            a_4.x += v4.x; a_4.y += v4.y; a_4.z += v4.z; a_4.w += v4.w;
            a_5.x += v5.x; a_5.y += v5.y; a_5.z += v5.z; a_5.w += v5.w;
            a_6.x += v6.x; a_6.y += v6.y; a_6.z += v6.z; a_6.w += v6.w;
            a_7.x += v7.x; a_7.y += v7.y; a_7.z += v7.z; a_7.w += v7.w;
        }
        for (; i < cnt; ++i) {
            float4 v = hb[(size_t)toks[i] * 256 + tid];
            a_0.x += v.x; a_0.y += v.y; a_0.z += v.z; a_0.w += v.w;
        }
        float4 acc;
        acc.x = ((a_0.x + a_1.x) + (a_2.x + a_3.x)) + ((a_4.x + a_5.x) + (a_6.x + a_7.x));
        acc.y = ((a_0.y + a_1.y) + (a_2.y + a_3.y)) + ((a_4.y + a_5.y) + (a_6.y + a_7.y));
        acc.z = ((a_0.z + a_1.z) + (a_2.z + a_3.z)) + ((a_4.z + a_5.z) + (a_6.z + a_7.z));
        acc.w = ((a_0.w + a_1.w) + (a_2.w + a_3.w)) + ((a_4.w + a_5.w) + (a_6.w + a_7.w));

        const int tgt_tok = rem_tok[b * NR + 52 * k];
        float4 bv = hb[(size_t)tgt_tok * 256 + tid];
        float inv = 1.0f / fmaxf((float)cnt, 1.0f);
        float4 o;
        o.x = bv.x + acc.x * inv; o.y = bv.y + acc.y * inv;
        o.z = bv.z + acc.z * inv; o.w = bv.w + acc.w * inv;
        ((float4*)&out[((size_t)(b * 65 + NSEL + k)) * D_])[tid] = o;
    } else {
        const int i2 = blk - B_ * CTX;
        const int b = i2 / NSEL, r = i2 % NSEL;
        int tok = dom_idx[b * NSEL + r];
        const float4* src = (const float4*)&hidden[((size_t)(b * L_ + tok)) * D_];
        ((float4*)&out[((size_t)(b * 65 + r)) * D_])[tid] = src[tid];
    }
}

extern "C" void kernel_launch(void* const* d_in, const int* in_sizes, int n_in,
                              void* d_out, int out_size, void* d_ws, size_t ws_size,
                              hipStream_t stream) {
    const float* attn   = (const float*)d_in[0];
    const float* hidden = (const float*)d_in[1];
    const float* metric = (const float*)d_in[2];
    const float* text   = (const float*)d_in[3];
    float* out = (float*)d_out;

    char* ws = (char*)d_ws;
    size_t off = 0;
    auto alloc = [&](size_t bytes) { void* p = ws + off; off = (off + bytes + 255) & ~(size_t)255; return p; };
    float* Sd_part    = (float*)alloc((size_t)4 * BL * 4);
    float* cos_arr    = (float*)alloc((size_t)BL * 4);
    int*   dom_idx    = (int*)  alloc((size_t)B_ * NSEL * 4);
    int*   rem_tok    = (int*)  alloc((size_t)B_ * NR * 4);
    int*   assign_tok = (int*)  alloc((size_t)B_ * NMERGE * 4);

    k_pre   <<<288 + BL / 4, 256, 0, stream>>>(attn, metric, text, Sd_part, cos_arr);
    k_select<<<B_, LP, 0, stream>>>(Sd_part, cos_arr, dom_idx, rem_tok);
    k_assign<<<B_ * 128, 256, 0, stream>>>(metric, rem_tok, assign_tok);
    k_out   <<<B_ * 65, 256, 0, stream>>>(hidden, dom_idx, rem_tok, assign_tok, out);
}